// Round 15
// baseline (128.921 us; speedup 1.0000x reference)
//
#include <hip/hip_runtime.h>
#include <hip/hip_bf16.h>

#define N_NODES 10000
#define N_EDGES 320000
#define E_TOT (N_EDGES + N_NODES)
#define D 256
#define VOCAB 28
#define NEG 0.2f
#define CAP 96   // max in-degree incl self-loop; Binomial(320k,1e-4) max ~58

typedef __attribute__((ext_vector_type(8))) short bf16x8;
typedef __attribute__((ext_vector_type(4))) float f32x4;

__device__ inline float blo(unsigned u) { return __uint_as_float(u << 16); }
__device__ inline float bhi(unsigned u) { return __uint_as_float(u & 0xFFFF0000u); }
__device__ inline unsigned short f2bu(float x) {
  __hip_bfloat16 b = __float2bfloat16(x);
  return *reinterpret_cast<unsigned short*>(&b);
}

// ---------------- prep: W1/W2 ^T bf16, zero counts, W@a vectors, layer-1 al,
//                  hv[28][256] = bf16(emb @ W0)  (vocab-collapsed layer-1 hlin) ----------------
__global__ __launch_bounds__(256) void prep_kernel(const float* __restrict__ W0,
                                                   const float* __restrict__ W1,
                                                   const float* __restrict__ W2,
                                                   const float* __restrict__ emb,
                                                   const float* __restrict__ as1,
                                                   const float* __restrict__ ad1,
                                                   const float* __restrict__ as2,
                                                   const float* __restrict__ ad2,
                                                   const float* __restrict__ as3,
                                                   const float* __restrict__ ad3,
                                                   const int* __restrict__ x,
                                                   unsigned short* __restrict__ T1,
                                                   unsigned short* __restrict__ T2,
                                                   unsigned short* __restrict__ hv,
                                                   float4* __restrict__ zbase,
                                                   float* __restrict__ waS2,
                                                   float* __restrict__ waD2,
                                                   float* __restrict__ waS3,
                                                   float* __restrict__ waD3,
                                                   float* __restrict__ al1_s,
                                                   float* __restrict__ al1_d) {
  int tid = threadIdx.x;
  int bid = blockIdx.x;
  if (bid < 32) {  // W1/W2 transpose + bf16
    __shared__ float t[64][65];
    int l = bid >> 4;  // 0 -> W1, 1 -> W2
    const float* W = (l == 0) ? W1 : W2;
    unsigned short* Wt = (l == 0) ? T1 : T2;
    int sub = bid & 15;
    int bk = (sub & 3) * 64;
    int bn = (sub >> 2) * 64;
    int row = tid >> 2;
    int cq = (tid & 3) * 16;
#pragma unroll
    for (int i = 0; i < 4; ++i) {
      float4 v = *reinterpret_cast<const float4*>(W + (size_t)(bk + row) * D + bn + cq + i * 4);
      t[row][cq + i * 4 + 0] = v.x; t[row][cq + i * 4 + 1] = v.y;
      t[row][cq + i * 4 + 2] = v.z; t[row][cq + i * 4 + 3] = v.w;
    }
    __syncthreads();
#pragma unroll
    for (int i = 0; i < 16; ++i)
      Wt[(size_t)(bn + row) * D + bk + cq + i] = f2bu(t[cq + i][row]);
  } else if (bid < 42) {   // zero counts: 10 blocks * 4096 B = 40,960 B
    zbase[(bid - 32) * 256 + tid] = float4{0.f, 0.f, 0.f, 0.f};
  } else if (bid == 42 || bid == 43) {  // waS/waD for layer 2 / 3
    const float* W = (bid == 42) ? W1 : W2;
    const float* as = (bid == 42) ? as2 : as3;
    const float* ad = (bid == 42) ? ad2 : ad3;
    float* oS = (bid == 42) ? waS2 : waS3;
    float* oD = (bid == 42) ? waD2 : waD3;
    float s = 0.f, d = 0.f;
    const float* row = W + (size_t)tid * D;
    for (int n = 0; n < D; ++n) {
      float w = row[n];
      s += w * as[n];
      d += w * ad[n];
    }
    oS[tid] = s; oD[tid] = d;
  } else if (bid == 44) {  // layer-1 al via 28-token table
    __shared__ float ws1[256], wd1[256], avs[VOCAB], avd[VOCAB];
    {
      float s = 0.f, d = 0.f;
      const float* row = W0 + (size_t)tid * D;
      for (int n = 0; n < D; ++n) {
        float w = row[n];
        s += w * as1[n];
        d += w * ad1[n];
      }
      ws1[tid] = s; wd1[tid] = d;
    }
    __syncthreads();
    int wid = tid >> 6, lane = tid & 63;
    for (int t = wid; t < VOCAB; t += 4) {
      float ps = 0.f, pd = 0.f;
      for (int k = lane; k < D; k += 64) {
        float e = emb[(size_t)t * D + k];
        ps += e * ws1[k];
        pd += e * wd1[k];
      }
#pragma unroll
      for (int off = 32; off; off >>= 1) {
        ps += __shfl_xor(ps, off);
        pd += __shfl_xor(pd, off);
      }
      if (lane == 0) { avs[t] = ps; avd[t] = pd; }
    }
    __syncthreads();
    for (int n = tid; n < N_NODES; n += 256) {
      int t = x[n];
      al1_s[n] = avs[t];
      al1_d[n] = avd[t];
    }
  } else {  // bid 45..72: hv[tok] = bf16(emb[tok] @ W0), thread = output column
    int tok = bid - 45;
    float s = 0.f;
    for (int k = 0; k < D; ++k)
      s += emb[(size_t)tok * D + k] * W0[(size_t)k * D + tid];
    hv[(size_t)tok * D + tid] = f2bu(s);
  }
}

// ---------------- bucket-CSR build ----------------
__global__ __launch_bounds__(256) void scatter_kernel(const int* __restrict__ ei,
                                                      int* __restrict__ counts,
                                                      int* __restrict__ csr) {
  int e = blockIdx.x * 256 + threadIdx.x;
  if (e >= E_TOT) return;
  int src, dst;
  if (e < N_EDGES) { src = ei[e]; dst = ei[N_EDGES + e]; }
  else             { src = e - N_EDGES; dst = src; }
  int pos = atomicAdd(&counts[dst], 1);
  csr[dst * CAP + pos] = src;
}

// ---------------- pure bf16 MFMA GEMM, 64x64 tiles, BK=64 ----------------
__global__ __launch_bounds__(256) void gemm_kernel(const unsigned short* __restrict__ Asrc,
                                                   const unsigned short* __restrict__ Bt,
                                                   unsigned short* __restrict__ C) {
  __shared__ unsigned short As[64][72];
  __shared__ unsigned short Bs[64][72];
  int t = threadIdx.x;
  int bm = blockIdx.x * 64;
  int bn = blockIdx.y * 64;
  int lane = t & 63, wid = t >> 6;
  int wr = (wid >> 1) * 32, wc = (wid & 1) * 32;
  int fr = lane & 15, fk = (lane >> 4) * 8;

  f32x4 acc[2][2] = {};
  for (int k0 = 0; k0 < D; k0 += 64) {
#pragma unroll
    for (int c = t; c < 512; c += 256) {
      int row = c >> 3, cc = (c & 7) * 8;
      int gr = bm + row;
      uint4 v = {0u, 0u, 0u, 0u};
      if (gr < N_NODES)
        v = *reinterpret_cast<const uint4*>(Asrc + (size_t)gr * D + k0 + cc);
      *reinterpret_cast<uint4*>(&As[row][cc]) = v;
      uint4 w = *reinterpret_cast<const uint4*>(Bt + (size_t)(bn + row) * D + k0 + cc);
      *reinterpret_cast<uint4*>(&Bs[row][cc]) = w;
    }
    __syncthreads();
#pragma unroll
    for (int ks = 0; ks < 2; ++ks) {
      bf16x8 a0 = *reinterpret_cast<const bf16x8*>(&As[wr + fr][ks * 32 + fk]);
      bf16x8 a1 = *reinterpret_cast<const bf16x8*>(&As[wr + 16 + fr][ks * 32 + fk]);
      bf16x8 b0 = *reinterpret_cast<const bf16x8*>(&Bs[wc + fr][ks * 32 + fk]);
      bf16x8 b1 = *reinterpret_cast<const bf16x8*>(&Bs[wc + 16 + fr][ks * 32 + fk]);
      acc[0][0] = __builtin_amdgcn_mfma_f32_16x16x32_bf16(a0, b0, acc[0][0], 0, 0, 0);
      acc[0][1] = __builtin_amdgcn_mfma_f32_16x16x32_bf16(a0, b1, acc[0][1], 0, 0, 0);
      acc[1][0] = __builtin_amdgcn_mfma_f32_16x16x32_bf16(a1, b0, acc[1][0], 0, 0, 0);
      acc[1][1] = __builtin_amdgcn_mfma_f32_16x16x32_bf16(a1, b1, acc[1][1], 0, 0, 0);
    }
    __syncthreads();
  }

  int orow = (lane >> 4) * 4;
#pragma unroll
  for (int m = 0; m < 2; ++m)
#pragma unroll
    for (int n = 0; n < 2; ++n)
#pragma unroll
      for (int r = 0; r < 4; ++r) {
        int gr = bm + wr + m * 16 + orow + r;
        if (gr < N_NODES)
          C[(size_t)gr * D + bn + wc + n * 16 + fr] = f2bu(acc[m][n][r]);
      }
}

// ---------------- fused edge-softmax + aggregate + bias + relu + residual ----------------
// 2 waves per dst: each wave owns half the edge range (halved latency chain);
// max/denom/accumulators combined via LDS. Block = 4 waves = 2 dst; grid 5000.
#define EDGE2(J)                                                                       \
  {                                                                                    \
    int s_ = ssh[ds][(J) + half];                                                      \
    float w_ = wsh[ds][(J) + half];                                                    \
    uint4 q_ = *reinterpret_cast<const uint4*>(hb_base + (size_t)s_ * D);              \
    a0 += w_ * blo(q_.x); a1 += w_ * bhi(q_.x); a2 += w_ * blo(q_.y);                  \
    a3 += w_ * bhi(q_.y); a4 += w_ * blo(q_.z); a5 += w_ * bhi(q_.z);                  \
    a6 += w_ * blo(q_.w); a7 += w_ * bhi(q_.w);                                        \
  }

__global__ __launch_bounds__(256) void agg_kernel(const int* __restrict__ csr,
                                                  const int* __restrict__ counts,
                                                  const float* __restrict__ al_s,
                                                  const float* __restrict__ al_d,
                                                  const unsigned short* __restrict__ hlin,
                                                  const float* __restrict__ bias,
                                                  const float* __restrict__ h_prev,
                                                  const int* __restrict__ xv,
                                                  const float* __restrict__ emb,
                                                  float* __restrict__ out_f,
                                                  unsigned short* __restrict__ out_b,
                                                  const float* __restrict__ waS_n,
                                                  const float* __restrict__ waD_n,
                                                  float* __restrict__ aln_s,
                                                  float* __restrict__ aln_d,
                                                  const int* __restrict__ idx_tab) {
  __shared__ int   ssh[2][CAP];
  __shared__ float wsh[2][CAP];
  __shared__ float redm[2][2];
  __shared__ float redd[2][2];
  __shared__ float accsh[2][8][64];
  int wid = threadIdx.x >> 6, lane = threadIdx.x & 63;
  int ds = wid >> 1;          // dst slot within block (0,1)
  int sub = wid & 1;          // which half-range this wave owns
  int dst = blockIdx.x * 2 + ds;  // grid 5000 * 2 == N_NODES exactly
  int cnt = counts[dst];
  int cnt2 = (cnt + 1) >> 1;
  int beg = sub * cnt2;
  int end = sub ? cnt : cnt2;
  const int* rowp = csr + (size_t)dst * CAP;
  float ad = al_d[dst];

  // stage 1: load src + leaky logit for own range; partial max
  float m = -1e30f;
  for (int j = beg + lane; j < end; j += 64) {
    int s = rowp[j];
    ssh[ds][j] = idx_tab ? idx_tab[s] : s;
    float v = al_s[s] + ad;
    v = (v >= 0.f) ? v : NEG * v;
    wsh[ds][j] = v;
    m = fmaxf(m, v);
  }
#pragma unroll
  for (int off = 32; off; off >>= 1) m = fmaxf(m, __shfl_xor(m, off));
  if (lane == 0) redm[ds][sub] = m;
  __syncthreads();
  m = fmaxf(redm[ds][0], redm[ds][1]);

  // stage 2: w = exp(logit - m) for own range; partial denom
  float denom = 0.f;
  for (int j = beg + lane; j < end; j += 64) {
    float w = __expf(wsh[ds][j] - m);
    wsh[ds][j] = w;
    denom += w;
  }
#pragma unroll
  for (int off = 32; off; off >>= 1) denom += __shfl_xor(denom, off);
  if (lane == 0) redd[ds][sub] = denom;
  __syncthreads();
  float inv = 1.0f / (redd[ds][0] + redd[ds][1]);

  // stage 3: gather own range (8-edge batches, 2 edges per load via half-wave)
  int half = lane >> 5, fl = lane & 31;
  const unsigned short* hb_base = hlin + fl * 8;
  float a0 = 0.f, a1 = 0.f, a2 = 0.f, a3 = 0.f;
  float a4 = 0.f, a5 = 0.f, a6 = 0.f, a7 = 0.f;
  int j = beg;
  for (; j + 8 <= end; j += 8) {
    EDGE2(j + 0) EDGE2(j + 2) EDGE2(j + 4) EDGE2(j + 6)
  }
  for (; j < end; j += 2) {
    int jj = j + half;
    bool valid = jj < end;
    int s0 = ssh[ds][valid ? jj : beg];
    float w0 = valid ? wsh[ds][jj] : 0.f;
    uint4 q0 = *reinterpret_cast<const uint4*>(hb_base + (size_t)s0 * D);
    a0 += w0 * blo(q0.x); a1 += w0 * bhi(q0.x); a2 += w0 * blo(q0.y); a3 += w0 * bhi(q0.y);
    a4 += w0 * blo(q0.z); a5 += w0 * bhi(q0.z); a6 += w0 * blo(q0.w); a7 += w0 * bhi(q0.w);
  }

  // stage 4: cross-wave accumulator combine; sub=0 finishes
  if (sub == 1) {
    accsh[ds][0][lane] = a0; accsh[ds][1][lane] = a1;
    accsh[ds][2][lane] = a2; accsh[ds][3][lane] = a3;
    accsh[ds][4][lane] = a4; accsh[ds][5][lane] = a5;
    accsh[ds][6][lane] = a6; accsh[ds][7][lane] = a7;
  }
  __syncthreads();
  if (sub == 0) {
    a0 += accsh[ds][0][lane]; a1 += accsh[ds][1][lane];
    a2 += accsh[ds][2][lane]; a3 += accsh[ds][3][lane];
    a4 += accsh[ds][4][lane]; a5 += accsh[ds][5][lane];
    a6 += accsh[ds][6][lane]; a7 += accsh[ds][7][lane];
    a0 += __shfl_xor(a0, 32); a1 += __shfl_xor(a1, 32);
    a2 += __shfl_xor(a2, 32); a3 += __shfl_xor(a3, 32);
    a4 += __shfl_xor(a4, 32); a5 += __shfl_xor(a5, 32);
    a6 += __shfl_xor(a6, 32); a7 += __shfl_xor(a7, 32);
    float b0 = half ? a4 : a0, b1 = half ? a5 : a1;
    float b2 = half ? a6 : a2, b3 = half ? a7 : a3;
    int fb = fl * 8 + half * 4;
    const float* hp_row = h_prev ? (h_prev + (size_t)dst * D)
                                 : (emb + (size_t)xv[dst] * D);
    float4 bb = *reinterpret_cast<const float4*>(bias + fb);
    float4 hp = *reinterpret_cast<const float4*>(hp_row + fb);
    float o0 = fmaxf(b0 * inv + bb.x, 0.f) + hp.x;
    float o1 = fmaxf(b1 * inv + bb.y, 0.f) + hp.y;
    float o2 = fmaxf(b2 * inv + bb.z, 0.f) + hp.z;
    float o3 = fmaxf(b3 * inv + bb.w, 0.f) + hp.w;
    float4 o = {o0, o1, o2, o3};
    *reinterpret_cast<float4*>(out_f + (size_t)dst * D + fb) = o;
    if (out_b) {
      uint2 p;
      p.x = (unsigned)f2bu(o0) | ((unsigned)f2bu(o1) << 16);
      p.y = (unsigned)f2bu(o2) | ((unsigned)f2bu(o3) << 16);
      *reinterpret_cast<uint2*>(out_b + (size_t)dst * D + fb) = p;
    }
    if (waS_n) {  // next-layer alphas from the fp32 output row in registers
      float4 s4 = *reinterpret_cast<const float4*>(waS_n + fb);
      float4 d4 = *reinterpret_cast<const float4*>(waD_n + fb);
      float ps = o0 * s4.x + o1 * s4.y + o2 * s4.z + o3 * s4.w;
      float pd = o0 * d4.x + o1 * d4.y + o2 * d4.z + o3 * d4.w;
#pragma unroll
      for (int off = 32; off; off >>= 1) {
        ps += __shfl_xor(ps, off);
        pd += __shfl_xor(pd, off);
      }
      if (lane == 0) { aln_s[dst] = ps; aln_d[dst] = pd; }
    }
  }
}

extern "C" void kernel_launch(void* const* d_in, const int* in_sizes, int n_in,
                              void* d_out, int out_size, void* d_ws, size_t ws_size,
                              hipStream_t stream) {
  const int*   x   = (const int*)d_in[0];
  const int*   ei  = (const int*)d_in[1];
  // d_in[2] = edge_attr (ignored by GATConv)
  const float* emb = (const float*)d_in[3];
  const float* W[3]    = {(const float*)d_in[4],  (const float*)d_in[8],  (const float*)d_in[12]};
  const float* asrc[3] = {(const float*)d_in[5],  (const float*)d_in[9],  (const float*)d_in[13]};
  const float* adst[3] = {(const float*)d_in[6],  (const float*)d_in[10], (const float*)d_in[14]};
  const float* bias[3] = {(const float*)d_in[7],  (const float*)d_in[11], (const float*)d_in[15]};

  char* ws = (char*)d_ws;
  float*          h    = (float*)(ws);                      // 10,240,000
  unsigned short* hb   = (unsigned short*)(ws + 10240000);  //  5,120,000
  unsigned short* hlin = (unsigned short*)(ws + 15360000);  //  5,120,000
  unsigned short* Wt1  = (unsigned short*)(ws + 20480000);  //    131,072
  unsigned short* Wt2  = (unsigned short*)(ws + 20611072);  //    131,072
  float* al_s[3] = {(float*)(ws + 20873216), (float*)(ws + 20914176), (float*)(ws + 20955136)};
  float* al_d[3] = {(float*)(ws + 20996096), (float*)(ws + 21037056), (float*)(ws + 21078016)};
  int* counts = (int*)(ws + 21118976);                      // 40,960 (zeroed in prep)
  int* csr    = (int*)(ws + 21241856);                      // 10000*96*4 = 3,840,000
  unsigned short* hv = (unsigned short*)(ws + 25081856);    // 28*256*2 = 14,336
  float* waS2 = (float*)(ws + 25096192);
  float* waD2 = (float*)(ws + 25097216);
  float* waS3 = (float*)(ws + 25098240);
  float* waD3 = (float*)(ws + 25099264);

  prep_kernel<<<73, 256, 0, stream>>>(W[0], W[1], W[2], emb,
                                      asrc[0], adst[0], asrc[1], adst[1], asrc[2], adst[2],
                                      x, Wt1, Wt2, hv,
                                      (float4*)counts, waS2, waD2, waS3, waD3,
                                      al_s[0], al_d[0]);

  scatter_kernel<<<(E_TOT + 255) / 256, 256, 0, stream>>>(ei, counts, csr);

  // Layer 1: NO GEMM — agg gathers from the 28-row L1-resident hv table via token ids
  agg_kernel<<<5000, 256, 0, stream>>>(csr, counts, al_s[0], al_d[0],
                                       hv, bias[0], nullptr, x, emb,
                                       h, hb, waS2, waD2, al_s[1], al_d[1], x);

  dim3 gemm_grid(157, 4);
  // Layer 2
  gemm_kernel<<<gemm_grid, 256, 0, stream>>>(hb, Wt1, hlin);
  agg_kernel<<<5000, 256, 0, stream>>>(csr, counts, al_s[1], al_d[1],
                                       hlin, bias[1], h, nullptr, nullptr,
                                       h, hb, waS3, waD3, al_s[2], al_d[2], nullptr);
  // Layer 3
  gemm_kernel<<<gemm_grid, 256, 0, stream>>>(hb, Wt2, hlin);
  agg_kernel<<<5000, 256, 0, stream>>>(csr, counts, al_s[2], al_d[2],
                                       hlin, bias[2], h, nullptr, nullptr,
                                       (float*)d_out, nullptr, nullptr, nullptr,
                                       nullptr, nullptr, nullptr);
}

// Round 16
// 118.323 us; speedup vs baseline: 1.0896x; 1.0896x over previous
//
#include <hip/hip_runtime.h>
#include <hip/hip_bf16.h>

#define N_NODES 10000
#define N_EDGES 320000
#define E_TOT (N_EDGES + N_NODES)
#define D 256
#define VOCAB 28
#define NEG 0.2f
#define CAP 96   // max in-degree incl self-loop; Binomial(320k,1e-4) max ~58

typedef __attribute__((ext_vector_type(8))) short bf16x8;
typedef __attribute__((ext_vector_type(4))) float f32x4;

__device__ inline float blo(unsigned u) { return __uint_as_float(u << 16); }
__device__ inline float bhi(unsigned u) { return __uint_as_float(u & 0xFFFF0000u); }
__device__ inline unsigned short f2bu(float x) {
  __hip_bfloat16 b = __float2bfloat16(x);
  return *reinterpret_cast<unsigned short*>(&b);
}

// ---------------- prep: W1/W2 ^T bf16, zero counts, W@a vectors, layer-1 al,
//                  hv[28][256] = bf16(emb @ W0)  (vocab-collapsed layer-1 hlin) ----------------
__global__ __launch_bounds__(256) void prep_kernel(const float* __restrict__ W0,
                                                   const float* __restrict__ W1,
                                                   const float* __restrict__ W2,
                                                   const float* __restrict__ emb,
                                                   const float* __restrict__ as1,
                                                   const float* __restrict__ ad1,
                                                   const float* __restrict__ as2,
                                                   const float* __restrict__ ad2,
                                                   const float* __restrict__ as3,
                                                   const float* __restrict__ ad3,
                                                   const int* __restrict__ x,
                                                   unsigned short* __restrict__ T1,
                                                   unsigned short* __restrict__ T2,
                                                   unsigned short* __restrict__ hv,
                                                   float4* __restrict__ zbase,
                                                   float* __restrict__ waS2,
                                                   float* __restrict__ waD2,
                                                   float* __restrict__ waS3,
                                                   float* __restrict__ waD3,
                                                   float* __restrict__ al1_s,
                                                   float* __restrict__ al1_d) {
  int tid = threadIdx.x;
  int bid = blockIdx.x;
  if (bid < 32) {  // W1/W2 transpose + bf16
    __shared__ float t[64][65];
    int l = bid >> 4;  // 0 -> W1, 1 -> W2
    const float* W = (l == 0) ? W1 : W2;
    unsigned short* Wt = (l == 0) ? T1 : T2;
    int sub = bid & 15;
    int bk = (sub & 3) * 64;
    int bn = (sub >> 2) * 64;
    int row = tid >> 2;
    int cq = (tid & 3) * 16;
#pragma unroll
    for (int i = 0; i < 4; ++i) {
      float4 v = *reinterpret_cast<const float4*>(W + (size_t)(bk + row) * D + bn + cq + i * 4);
      t[row][cq + i * 4 + 0] = v.x; t[row][cq + i * 4 + 1] = v.y;
      t[row][cq + i * 4 + 2] = v.z; t[row][cq + i * 4 + 3] = v.w;
    }
    __syncthreads();
#pragma unroll
    for (int i = 0; i < 16; ++i)
      Wt[(size_t)(bn + row) * D + bk + cq + i] = f2bu(t[cq + i][row]);
  } else if (bid < 42) {   // zero counts: 10 blocks * 4096 B = 40,960 B
    zbase[(bid - 32) * 256 + tid] = float4{0.f, 0.f, 0.f, 0.f};
  } else if (bid == 42 || bid == 43) {  // waS/waD for layer 2 / 3
    const float* W = (bid == 42) ? W1 : W2;
    const float* as = (bid == 42) ? as2 : as3;
    const float* ad = (bid == 42) ? ad2 : ad3;
    float* oS = (bid == 42) ? waS2 : waS3;
    float* oD = (bid == 42) ? waD2 : waD3;
    float s = 0.f, d = 0.f;
    const float* row = W + (size_t)tid * D;
    for (int n = 0; n < D; ++n) {
      float w = row[n];
      s += w * as[n];
      d += w * ad[n];
    }
    oS[tid] = s; oD[tid] = d;
  } else if (bid == 44) {  // layer-1 al via 28-token table
    __shared__ float ws1[256], wd1[256], avs[VOCAB], avd[VOCAB];
    {
      float s = 0.f, d = 0.f;
      const float* row = W0 + (size_t)tid * D;
      for (int n = 0; n < D; ++n) {
        float w = row[n];
        s += w * as1[n];
        d += w * ad1[n];
      }
      ws1[tid] = s; wd1[tid] = d;
    }
    __syncthreads();
    int wid = tid >> 6, lane = tid & 63;
    for (int t = wid; t < VOCAB; t += 4) {
      float ps = 0.f, pd = 0.f;
      for (int k = lane; k < D; k += 64) {
        float e = emb[(size_t)t * D + k];
        ps += e * ws1[k];
        pd += e * wd1[k];
      }
#pragma unroll
      for (int off = 32; off; off >>= 1) {
        ps += __shfl_xor(ps, off);
        pd += __shfl_xor(pd, off);
      }
      if (lane == 0) { avs[t] = ps; avd[t] = pd; }
    }
    __syncthreads();
    for (int n = tid; n < N_NODES; n += 256) {
      int t = x[n];
      al1_s[n] = avs[t];
      al1_d[n] = avd[t];
    }
  } else {  // bid 45..72: hv[tok] = bf16(emb[tok] @ W0), thread = output column
    int tok = bid - 45;
    float s = 0.f;
    for (int k = 0; k < D; ++k)
      s += emb[(size_t)tok * D + k] * W0[(size_t)k * D + tid];
    hv[(size_t)tok * D + tid] = f2bu(s);
  }
}

// ---------------- bucket-CSR build ----------------
__global__ __launch_bounds__(256) void scatter_kernel(const int* __restrict__ ei,
                                                      int* __restrict__ counts,
                                                      int* __restrict__ csr) {
  int e = blockIdx.x * 256 + threadIdx.x;
  if (e >= E_TOT) return;
  int src, dst;
  if (e < N_EDGES) { src = ei[e]; dst = ei[N_EDGES + e]; }
  else             { src = e - N_EDGES; dst = src; }
  int pos = atomicAdd(&counts[dst], 1);
  csr[dst * CAP + pos] = src;
}

// ---------------- pure bf16 MFMA GEMM, 64x64 tiles, BK=64 ----------------
__global__ __launch_bounds__(256) void gemm_kernel(const unsigned short* __restrict__ Asrc,
                                                   const unsigned short* __restrict__ Bt,
                                                   unsigned short* __restrict__ C) {
  __shared__ unsigned short As[64][72];
  __shared__ unsigned short Bs[64][72];
  int t = threadIdx.x;
  int bm = blockIdx.x * 64;
  int bn = blockIdx.y * 64;
  int lane = t & 63, wid = t >> 6;
  int wr = (wid >> 1) * 32, wc = (wid & 1) * 32;
  int fr = lane & 15, fk = (lane >> 4) * 8;

  f32x4 acc[2][2] = {};
  for (int k0 = 0; k0 < D; k0 += 64) {
#pragma unroll
    for (int c = t; c < 512; c += 256) {
      int row = c >> 3, cc = (c & 7) * 8;
      int gr = bm + row;
      uint4 v = {0u, 0u, 0u, 0u};
      if (gr < N_NODES)
        v = *reinterpret_cast<const uint4*>(Asrc + (size_t)gr * D + k0 + cc);
      *reinterpret_cast<uint4*>(&As[row][cc]) = v;
      uint4 w = *reinterpret_cast<const uint4*>(Bt + (size_t)(bn + row) * D + k0 + cc);
      *reinterpret_cast<uint4*>(&Bs[row][cc]) = w;
    }
    __syncthreads();
#pragma unroll
    for (int ks = 0; ks < 2; ++ks) {
      bf16x8 a0 = *reinterpret_cast<const bf16x8*>(&As[wr + fr][ks * 32 + fk]);
      bf16x8 a1 = *reinterpret_cast<const bf16x8*>(&As[wr + 16 + fr][ks * 32 + fk]);
      bf16x8 b0 = *reinterpret_cast<const bf16x8*>(&Bs[wc + fr][ks * 32 + fk]);
      bf16x8 b1 = *reinterpret_cast<const bf16x8*>(&Bs[wc + 16 + fr][ks * 32 + fk]);
      acc[0][0] = __builtin_amdgcn_mfma_f32_16x16x32_bf16(a0, b0, acc[0][0], 0, 0, 0);
      acc[0][1] = __builtin_amdgcn_mfma_f32_16x16x32_bf16(a0, b1, acc[0][1], 0, 0, 0);
      acc[1][0] = __builtin_amdgcn_mfma_f32_16x16x32_bf16(a1, b0, acc[1][0], 0, 0, 0);
      acc[1][1] = __builtin_amdgcn_mfma_f32_16x16x32_bf16(a1, b1, acc[1][1], 0, 0, 0);
    }
    __syncthreads();
  }

  int orow = (lane >> 4) * 4;
#pragma unroll
  for (int m = 0; m < 2; ++m)
#pragma unroll
    for (int n = 0; n < 2; ++n)
#pragma unroll
      for (int r = 0; r < 4; ++r) {
        int gr = bm + wr + m * 16 + orow + r;
        if (gr < N_NODES)
          C[(size_t)gr * D + bn + wc + n * 16 + fr] = f2bu(acc[m][n][r]);
      }
}

// ---------------- fused edge-softmax + aggregate + bias + relu + residual ----------------
// idx_tab != null (layer 1): gather index = idx_tab[src] (token id into 28-row hv table).
// Optional epilogue: next-layer alphas al_next = o . waS_next / waD_next.
__global__ __launch_bounds__(256) void agg_kernel(const int* __restrict__ csr,
                                                  const int* __restrict__ counts,
                                                  const float* __restrict__ al_s,
                                                  const float* __restrict__ al_d,
                                                  const unsigned short* __restrict__ hlin,
                                                  const float* __restrict__ bias,
                                                  const float* __restrict__ h_prev,
                                                  const int* __restrict__ xv,
                                                  const float* __restrict__ emb,
                                                  float* __restrict__ out_f,
                                                  unsigned short* __restrict__ out_b,
                                                  const float* __restrict__ waS_n,
                                                  const float* __restrict__ waD_n,
                                                  float* __restrict__ aln_s,
                                                  float* __restrict__ aln_d,
                                                  const int* __restrict__ idx_tab) {
  __shared__ int   ssh[4][CAP];
  __shared__ float wsh[4][CAP];
  int wid = threadIdx.x >> 6, lane = threadIdx.x & 63;
  int dst = blockIdx.x * 4 + wid;
  if (dst >= N_NODES) return;
  int cnt = counts[dst];
  const int* rowp = csr + (size_t)dst * CAP;
  float ad = al_d[dst];

  float m = -1e30f;
  for (int j = lane; j < cnt; j += 64) {
    int s = rowp[j];
    ssh[wid][j] = idx_tab ? idx_tab[s] : s;
    float v = al_s[s] + ad;
    v = (v >= 0.f) ? v : NEG * v;
    wsh[wid][j] = v;
    m = fmaxf(m, v);
  }
#pragma unroll
  for (int off = 32; off; off >>= 1) m = fmaxf(m, __shfl_xor(m, off));

  float denom = 0.f;
  for (int j = lane; j < cnt; j += 64) {
    float w = __expf(wsh[wid][j] - m);
    wsh[wid][j] = w;
    denom += w;
  }
#pragma unroll
  for (int off = 32; off; off >>= 1) denom += __shfl_xor(denom, off);
  float inv = 1.0f / denom;

  int half = lane >> 5, fl = lane & 31;
  const unsigned short* hb_base = hlin + fl * 8;
  float a0 = 0.f, a1 = 0.f, a2 = 0.f, a3 = 0.f;
  float a4 = 0.f, a5 = 0.f, a6 = 0.f, a7 = 0.f;
  int j = 0;
  for (; j + 8 <= cnt; j += 8) {
    int s0 = ssh[wid][j + 0 + half];
    int s1 = ssh[wid][j + 2 + half];
    int s2 = ssh[wid][j + 4 + half];
    int s3 = ssh[wid][j + 6 + half];
    float w0 = wsh[wid][j + 0 + half];
    float w1 = wsh[wid][j + 2 + half];
    float w2 = wsh[wid][j + 4 + half];
    float w3 = wsh[wid][j + 6 + half];
    uint4 q0 = *reinterpret_cast<const uint4*>(hb_base + (size_t)s0 * D);
    uint4 q1 = *reinterpret_cast<const uint4*>(hb_base + (size_t)s1 * D);
    uint4 q2 = *reinterpret_cast<const uint4*>(hb_base + (size_t)s2 * D);
    uint4 q3 = *reinterpret_cast<const uint4*>(hb_base + (size_t)s3 * D);
    a0 += w0 * blo(q0.x); a1 += w0 * bhi(q0.x); a2 += w0 * blo(q0.y); a3 += w0 * bhi(q0.y);
    a4 += w0 * blo(q0.z); a5 += w0 * bhi(q0.z); a6 += w0 * blo(q0.w); a7 += w0 * bhi(q0.w);
    a0 += w1 * blo(q1.x); a1 += w1 * bhi(q1.x); a2 += w1 * blo(q1.y); a3 += w1 * bhi(q1.y);
    a4 += w1 * blo(q1.z); a5 += w1 * bhi(q1.z); a6 += w1 * blo(q1.w); a7 += w1 * bhi(q1.w);
    a0 += w2 * blo(q2.x); a1 += w2 * bhi(q2.x); a2 += w2 * blo(q2.y); a3 += w2 * bhi(q2.y);
    a4 += w2 * blo(q2.z); a5 += w2 * bhi(q2.z); a6 += w2 * blo(q2.w); a7 += w2 * bhi(q2.w);
    a0 += w3 * blo(q3.x); a1 += w3 * bhi(q3.x); a2 += w3 * blo(q3.y); a3 += w3 * bhi(q3.y);
    a4 += w3 * blo(q3.z); a5 += w3 * bhi(q3.z); a6 += w3 * blo(q3.w); a7 += w3 * bhi(q3.w);
  }
  for (; j < cnt; j += 2) {
    int jj = j + half;
    bool valid = jj < cnt;
    int s0 = ssh[wid][valid ? jj : 0];
    float w0 = valid ? wsh[wid][jj] : 0.f;
    uint4 q0 = *reinterpret_cast<const uint4*>(hb_base + (size_t)s0 * D);
    a0 += w0 * blo(q0.x); a1 += w0 * bhi(q0.x); a2 += w0 * blo(q0.y); a3 += w0 * bhi(q0.y);
    a4 += w0 * blo(q0.z); a5 += w0 * bhi(q0.z); a6 += w0 * blo(q0.w); a7 += w0 * bhi(q0.w);
  }
  a0 += __shfl_xor(a0, 32); a1 += __shfl_xor(a1, 32);
  a2 += __shfl_xor(a2, 32); a3 += __shfl_xor(a3, 32);
  a4 += __shfl_xor(a4, 32); a5 += __shfl_xor(a5, 32);
  a6 += __shfl_xor(a6, 32); a7 += __shfl_xor(a7, 32);
  float b0 = half ? a4 : a0, b1 = half ? a5 : a1;
  float b2 = half ? a6 : a2, b3 = half ? a7 : a3;
  int fb = fl * 8 + half * 4;
  const float* hp_row = h_prev ? (h_prev + (size_t)dst * D)
                               : (emb + (size_t)xv[dst] * D);
  float4 bb = *reinterpret_cast<const float4*>(bias + fb);
  float4 hp = *reinterpret_cast<const float4*>(hp_row + fb);
  float o0 = fmaxf(b0 * inv + bb.x, 0.f) + hp.x;
  float o1 = fmaxf(b1 * inv + bb.y, 0.f) + hp.y;
  float o2 = fmaxf(b2 * inv + bb.z, 0.f) + hp.z;
  float o3 = fmaxf(b3 * inv + bb.w, 0.f) + hp.w;
  float4 o = {o0, o1, o2, o3};
  *reinterpret_cast<float4*>(out_f + (size_t)dst * D + fb) = o;
  if (out_b) {
    uint2 p;
    p.x = (unsigned)f2bu(o0) | ((unsigned)f2bu(o1) << 16);
    p.y = (unsigned)f2bu(o2) | ((unsigned)f2bu(o3) << 16);
    *reinterpret_cast<uint2*>(out_b + (size_t)dst * D + fb) = p;
  }
  if (waS_n) {  // next-layer alphas from the fp32 output row in registers
    float4 s4 = *reinterpret_cast<const float4*>(waS_n + fb);
    float4 d4 = *reinterpret_cast<const float4*>(waD_n + fb);
    float ps = o0 * s4.x + o1 * s4.y + o2 * s4.z + o3 * s4.w;
    float pd = o0 * d4.x + o1 * d4.y + o2 * d4.z + o3 * d4.w;
#pragma unroll
    for (int off = 32; off; off >>= 1) {
      ps += __shfl_xor(ps, off);
      pd += __shfl_xor(pd, off);
    }
    if (lane == 0) { aln_s[dst] = ps; aln_d[dst] = pd; }
  }
}

extern "C" void kernel_launch(void* const* d_in, const int* in_sizes, int n_in,
                              void* d_out, int out_size, void* d_ws, size_t ws_size,
                              hipStream_t stream) {
  const int*   x   = (const int*)d_in[0];
  const int*   ei  = (const int*)d_in[1];
  // d_in[2] = edge_attr (ignored by GATConv)
  const float* emb = (const float*)d_in[3];
  const float* W[3]    = {(const float*)d_in[4],  (const float*)d_in[8],  (const float*)d_in[12]};
  const float* asrc[3] = {(const float*)d_in[5],  (const float*)d_in[9],  (const float*)d_in[13]};
  const float* adst[3] = {(const float*)d_in[6],  (const float*)d_in[10], (const float*)d_in[14]};
  const float* bias[3] = {(const float*)d_in[7],  (const float*)d_in[11], (const float*)d_in[15]};

  char* ws = (char*)d_ws;
  float*          h    = (float*)(ws);                      // 10,240,000
  unsigned short* hb   = (unsigned short*)(ws + 10240000);  //  5,120,000
  unsigned short* hlin = (unsigned short*)(ws + 15360000);  //  5,120,000
  unsigned short* Wt1  = (unsigned short*)(ws + 20480000);  //    131,072
  unsigned short* Wt2  = (unsigned short*)(ws + 20611072);  //    131,072
  float* al_s[3] = {(float*)(ws + 20873216), (float*)(ws + 20914176), (float*)(ws + 20955136)};
  float* al_d[3] = {(float*)(ws + 20996096), (float*)(ws + 21037056), (float*)(ws + 21078016)};
  int* counts = (int*)(ws + 21118976);                      // 40,960 (zeroed in prep)
  int* csr    = (int*)(ws + 21241856);                      // 10000*96*4 = 3,840,000
  unsigned short* hv = (unsigned short*)(ws + 25081856);    // 28*256*2 = 14,336
  float* waS2 = (float*)(ws + 25096192);
  float* waD2 = (float*)(ws + 25097216);
  float* waS3 = (float*)(ws + 25098240);
  float* waD3 = (float*)(ws + 25099264);

  prep_kernel<<<73, 256, 0, stream>>>(W[0], W[1], W[2], emb,
                                      asrc[0], adst[0], asrc[1], adst[1], asrc[2], adst[2],
                                      x, Wt1, Wt2, hv,
                                      (float4*)counts, waS2, waD2, waS3, waD3,
                                      al_s[0], al_d[0]);

  scatter_kernel<<<(E_TOT + 255) / 256, 256, 0, stream>>>(ei, counts, csr);

  // Layer 1: NO GEMM — agg gathers from the 28-row L1-resident hv table via token ids
  agg_kernel<<<2500, 256, 0, stream>>>(csr, counts, al_s[0], al_d[0],
                                       hv, bias[0], nullptr, x, emb,
                                       h, hb, waS2, waD2, al_s[1], al_d[1], x);

  dim3 gemm_grid(157, 4);
  // Layer 2
  gemm_kernel<<<gemm_grid, 256, 0, stream>>>(hb, Wt1, hlin);
  agg_kernel<<<2500, 256, 0, stream>>>(csr, counts, al_s[1], al_d[1],
                                       hlin, bias[1], h, nullptr, nullptr,
                                       h, hb, waS3, waD3, al_s[2], al_d[2], nullptr);
  // Layer 3
  gemm_kernel<<<gemm_grid, 256, 0, stream>>>(hb, Wt2, hlin);
  agg_kernel<<<2500, 256, 0, stream>>>(csr, counts, al_s[2], al_d[2],
                                       hlin, bias[2], h, nullptr, nullptr,
                                       (float*)d_out, nullptr, nullptr, nullptr,
                                       nullptr, nullptr, nullptr);
}